// Round 4
// baseline (64.246 us; speedup 1.0000x reference)
//
#include <hip/hip_runtime.h>
#include <math.h>

// YOLOv3 detection-head decode.
// prediction: [B=32, 255, 52, 52] f32 ; anchors: [3,2] f32
// out: [B, 52*52*3, 85] f32 ; flat out index e within a (b,gj) slice:
//   e = gi*255 + c, c = a*85+attr; slice = b*52+gj; slice output = 13,260
//   contiguous floats (16B-aligned, 53,040 B).
//
// Block = (b, gj, chunk): chunk boundaries [0,3316,6632,9948,13260] are all
// float4-exact AND 16B-aligned. LDS = chunk in OUTPUT order (13,264 B ->
// 8 blocks/CU, 100% occupancy cap).
//   Load phase : 255 rows x 4 aligned float4 (16-gi window g0=12q covers the
//                chunk's gi range), scatter into flat LDS (guarded).
//   Write phase: ~3.24 independent iters/thread, ds_read_b128 (1KB/wave
//                contiguous, conflict-free) + in-reg decode + dwordx4 store
//                (1KB/wave, sequential). Full MLP, wide both directions.

#define BB 32
#define GG 52
#define NROWS 255
#define PLANE (GG * GG)        // 2704
#define SLICE_N (GG * NROWS)   // 13260
#define CHUNK 3316             // floats per chunk (q<3); q==3 -> 3312
#define L2E 1.442695040889f

__device__ __forceinline__ float fast_sigmoid(float x) {
    return __builtin_amdgcn_rcpf(1.0f + __builtin_amdgcn_exp2f(-L2E * x));
}

__global__ __launch_bounds__(256, 8)
void detect_decode_kernel(const float* __restrict__ in,
                          const float* __restrict__ anchors,
                          float* __restrict__ out) {
    __shared__ float tile[CHUNK];   // 13,264 B

    const int blk   = blockIdx.x;
    const int q     = blk & 3;
    const int slice = blk >> 2;          // b*GG + gj
    const int b  = slice / GG;
    const int gj = slice - b * GG;
    const int t  = threadIdx.x;

    const int e0  = q * CHUNK;                 // 0,3316,6632,9948
    const int len = (q == 3) ? 3312 : CHUNK;
    const int g0  = 12 * q;                    // gi-window [g0, g0+16)

    // anchors (pixel units: (anchor/stride)*stride = anchor)
    const float a0x = anchors[0], a0y = anchors[1];
    const float a1x = anchors[2], a1y = anchors[3];
    const float a2x = anchors[4], a2y = anchors[5];

    // ---- load: 255 rows x 4 float4 (16 gi), scatter to flat LDS ----
    const float* __restrict__ src = in + (size_t)b * NROWS * PLANE + gj * GG + g0;

    #pragma unroll
    for (int it = 0; it < 4; ++it) {
        const int idx = t + it * 256;          // 0..1019 (last iter partial)
        if (idx < NROWS * 4) {
            const int c  = idx >> 2;
            const int qq = idx & 3;
            const float4 v =
                *reinterpret_cast<const float4*>(src + (size_t)c * PLANE + 4 * qq);
            // e = g*255 + c, g = g0 + 4*qq + k
            const int eb = (g0 + 4 * qq) * NROWS + c - e0;
            if ((unsigned)(eb          ) < (unsigned)len) tile[eb          ] = v.x;
            if ((unsigned)(eb +   NROWS) < (unsigned)len) tile[eb +   NROWS] = v.y;
            if ((unsigned)(eb + 2*NROWS) < (unsigned)len) tile[eb + 2*NROWS] = v.z;
            if ((unsigned)(eb + 3*NROWS) < (unsigned)len) tile[eb + 3*NROWS] = v.w;
        }
    }

    __syncthreads();

    // ---- write: stream chunk as float4, decode in-register ----
    float* __restrict__ dst = out + (size_t)slice * SLICE_N + e0;
    const int nq = len >> 2;                   // 829 or 828

    for (int i = t; i < nq; i += 256) {
        const float4 v = *reinterpret_cast<const float4*>(&tile[4 * i]);
        const int e  = e0 + 4 * i;
        const int gi0 = e / NROWS;             // magic div
        const int c0  = e - gi0 * NROWS;

        float r[4];
        const float xs[4] = {v.x, v.y, v.z, v.w};
        #pragma unroll
        for (int k = 0; k < 4; ++k) {
            int c  = c0 + k;
            int gi = gi0;
            if (c >= NROWS) { c -= NROWS; gi += 1; }
            const int a    = (c >= 170) ? 2 : (c >= 85 ? 1 : 0);
            const int attr = c - a * 85;

            const float x = xs[k];
            const float s  = fast_sigmoid(x);
            const float ex = __builtin_amdgcn_exp2f(L2E * x);
            const float ancx = (a == 0) ? a0x : (a == 1) ? a1x : a2x;
            const float ancy = (a == 0) ? a0y : (a == 1) ? a1y : a2y;

            float r_;
            if (attr >= 4)      r_ = s;
            else if (attr == 0) r_ = (s + (float)gi) * 8.0f;
            else if (attr == 1) r_ = (s + (float)gj) * 8.0f;
            else if (attr == 2) r_ = ex * ancx;
            else                r_ = ex * ancy;
            r[k] = r_;
        }

        float4 o; o.x = r[0]; o.y = r[1]; o.z = r[2]; o.w = r[3];
        *reinterpret_cast<float4*>(dst + 4 * i) = o;
    }
}

extern "C" void kernel_launch(void* const* d_in, const int* in_sizes, int n_in,
                              void* d_out, int out_size, void* d_ws, size_t ws_size,
                              hipStream_t stream) {
    const float* pred    = (const float*)d_in[0];
    const float* anchors = (const float*)d_in[1];
    float* out = (float*)d_out;

    const int nblocks = BB * GG * 4;   // 6656: four flat chunks per (b, gj)
    detect_decode_kernel<<<nblocks, 256, 0, stream>>>(pred, anchors, out);
}

// Round 5
// 46.000 us; speedup vs baseline: 1.3967x; 1.3967x over previous
//
#include <hip/hip_runtime.h>
#include <math.h>

// YOLOv3 detection-head decode.
// prediction: [B=32, 255, 52, 52] f32 ; anchors: [3,2] f32
// out: [B, 52*52*3, 85] f32 ; within a (b,gj) slice the output is 13,260
// contiguous floats: e = gi*255 + c, c = a*85+attr. Slice = 53,040 B,
// 16B-aligned, = 3315 exact float4.
//
// Block = one (b,gj) slice, 1024 threads, LDS = slice in OUTPUT order
// (53,040 B). 2 blocks/CU (106 KB LDS, 2048 thr) = 100% occupancy.
//   Load : 255 full rows x 13 aligned float4, row-exclusive (zero overlap,
//          zero over-fetch), scatter to LDS (~2-way write conflicts = free).
//   Write: 3315 float4, ~3.24 indep iters/thread: ds_read_b128 (conflict-
//          free) -> in-reg attr decode -> global_store_dwordx4 into one
//          contiguous 53 KB span. No guards, full MLP both phases.

#define BB 32
#define GG 52
#define NROWS 255
#define PLANE (GG * GG)        // 2704
#define SLICE_N (GG * NROWS)   // 13260 floats per slice
#define NQ4 (SLICE_N / 4)      // 3315 float4 per slice
#define L2E 1.442695040889f

__device__ __forceinline__ float fast_sigmoid(float x) {
    return __builtin_amdgcn_rcpf(1.0f + __builtin_amdgcn_exp2f(-L2E * x));
}

__global__ __launch_bounds__(1024, 8)   // 8 waves/SIMD -> 2 blocks/CU
void detect_decode_kernel(const float* __restrict__ in,
                          const float* __restrict__ anchors,
                          float* __restrict__ out) {
    __shared__ float tile[SLICE_N];     // 53,040 B, output order

    const int slice = blockIdx.x;       // b*GG + gj
    const int b  = slice / GG;
    const int gj = slice - b * GG;
    const int t  = threadIdx.x;

    const float a0x = anchors[0], a0y = anchors[1];
    const float a1x = anchors[2], a1y = anchors[3];
    const float a2x = anchors[4], a2y = anchors[5];

    // ---- load: 255 rows x 13 float4 (row-exclusive, aligned) ----
    const float* __restrict__ src = in + (size_t)b * NROWS * PLANE + gj * GG;

    float4 v[4];
    int   rowv[4], qv[4];
    #pragma unroll
    for (int it = 0; it < 4; ++it) {
        const int idx = t + it * 1024;           // 0..3314 (last iter partial)
        if (idx < NROWS * 13) {
            const int row = idx / 13;            // magic mul
            const int q   = idx - row * 13;
            rowv[it] = row; qv[it] = q;
            v[it] = *reinterpret_cast<const float4*>(src + (size_t)row * PLANE + 4 * q);
        }
    }
    #pragma unroll
    for (int it = 0; it < 4; ++it) {
        const int idx = t + it * 1024;
        if (idx < NROWS * 13) {
            // element (c=row, g=4q+k) -> e = g*255 + c
            const int e = (4 * qv[it]) * NROWS + rowv[it];
            tile[e            ] = v[it].x;
            tile[e +     NROWS] = v[it].y;
            tile[e + 2 * NROWS] = v[it].z;
            tile[e + 3 * NROWS] = v[it].w;
        }
    }

    __syncthreads();

    // ---- write: stream slice as float4, decode in-register ----
    float* __restrict__ dst = out + (size_t)slice * SLICE_N;

    float4 u[4];
    #pragma unroll
    for (int it = 0; it < 4; ++it) {
        const int i = t + it * 1024;
        if (i < NQ4)
            u[it] = *reinterpret_cast<const float4*>(&tile[4 * i]);
    }
    #pragma unroll
    for (int it = 0; it < 4; ++it) {
        const int i = t + it * 1024;
        if (i < NQ4) {
            const int e   = 4 * i;
            const int gi0 = e / NROWS;           // magic div
            const int c0  = e - gi0 * NROWS;

            const float xs[4] = {u[it].x, u[it].y, u[it].z, u[it].w};
            float r[4];
            #pragma unroll
            for (int k = 0; k < 4; ++k) {
                int c  = c0 + k;
                int gi = gi0;
                if (c >= NROWS) { c -= NROWS; gi += 1; }
                const int a    = (c >= 170) ? 2 : (c >= 85 ? 1 : 0);
                const int attr = c - a * 85;

                const float x  = xs[k];
                const float s  = fast_sigmoid(x);
                const float ex = __builtin_amdgcn_exp2f(L2E * x);
                const float ancx = (a == 0) ? a0x : (a == 1) ? a1x : a2x;
                const float ancy = (a == 0) ? a0y : (a == 1) ? a1y : a2y;

                float r_;
                if (attr >= 4)      r_ = s;
                else if (attr == 0) r_ = (s + (float)gi) * 8.0f;
                else if (attr == 1) r_ = (s + (float)gj) * 8.0f;
                else if (attr == 2) r_ = ex * ancx;
                else                r_ = ex * ancy;
                r[k] = r_;
            }

            float4 o; o.x = r[0]; o.y = r[1]; o.z = r[2]; o.w = r[3];
            *reinterpret_cast<float4*>(dst + 4 * i) = o;
        }
    }
}

extern "C" void kernel_launch(void* const* d_in, const int* in_sizes, int n_in,
                              void* d_out, int out_size, void* d_ws, size_t ws_size,
                              hipStream_t stream) {
    const float* pred    = (const float*)d_in[0];
    const float* anchors = (const float*)d_in[1];
    float* out = (float*)d_out;

    const int nblocks = BB * GG;   // 1664: one block per (b, gj) slice
    detect_decode_kernel<<<nblocks, 1024, 0, stream>>>(pred, anchors, out);
}

// Round 7
// 44.484 us; speedup vs baseline: 1.4443x; 1.0341x over previous
//
#include <hip/hip_runtime.h>
#include <math.h>

// YOLOv3 detection-head decode.
// prediction: [B=32, 255, 52, 52] f32 ; anchors: [3,2] f32
// out: [B, 52*52*3, 85] f32 ; per (b,gj) slice output is 13,260 contiguous
// floats, e = gi*255 + c (c = a*85+attr).
//
// Block = (slice, gi-chunk), chunks of {16,12,12,12} gi (multiples of 4 gi
// => float4-exact and 16B-aligned on BOTH input rows and output span).
//   Load : 255 rows x {4|3} aligned float4, row-exclusive (zero over-fetch),
//          scatter to output-order flat LDS (16,320 B max -> 8 blocks/CU,
//          100% occupancy, fine-grained barriers).
//   Write: {1020|765} float4: ds_read_b128 (contiguous, conflict-free) ->
//          in-reg attr decode -> nontemporal global_store_dwordx4 into one
//          contiguous aligned span.
// XCD swizzle: a slice's 4 chunks run on the SAME XCD back-to-back so
// boundary input lines are L2-shared, not refetched cross-XCD.

#define BB 32
#define GG 52
#define NROWS 255
#define PLANE (GG * GG)        // 2704
#define SLICE_N (GG * NROWS)   // 13260
#define L2E 1.442695040889f

typedef float f32x4 __attribute__((ext_vector_type(4)));

__device__ __forceinline__ float fast_sigmoid(float x) {
    return __builtin_amdgcn_rcpf(1.0f + __builtin_amdgcn_exp2f(-L2E * x));
}

template<int GI0, int NG>
__device__ __forceinline__ void decode_body(int slice, int t,
                                            const float* __restrict__ in,
                                            const float* __restrict__ anchors,
                                            float* __restrict__ out,
                                            float* __restrict__ tile) {
    const int b  = slice / GG;
    const int gj = slice - b * GG;

    constexpr int NQROW = NG / 4;            // float4 per row: 4 or 3
    constexpr int TOTQ  = NROWS * NQROW;     // 1020 or 765
    constexpr int NIT   = (TOTQ + 255) / 256;

    // anchors: uniform scalar loads, overlap with staging
    const float a0x = anchors[0], a0y = anchors[1];
    const float a1x = anchors[2], a1y = anchors[3];
    const float a2x = anchors[4], a2y = anchors[5];

    // ---- load: row-exclusive aligned float4, scatter to output order ----
    const float* __restrict__ src =
        in + (size_t)b * NROWS * PLANE + gj * GG + GI0;

    #pragma unroll
    for (int it = 0; it < NIT; ++it) {
        const int idx = t + it * 256;
        if (it < NIT - 1 || idx < TOTQ) {
            int row, q;
            if constexpr (NQROW == 4) { row = idx >> 2; q = idx & 3; }
            else                      { row = idx / 3;  q = idx - row * 3; }
            const f32x4 v =
                *reinterpret_cast<const f32x4*>(src + (size_t)row * PLANE + 4 * q);
            const int e = (4 * q) * NROWS + row;   // gi_local = 4q+k, c = row
            tile[e            ] = v.x;
            tile[e +     NROWS] = v.y;
            tile[e + 2 * NROWS] = v.z;
            tile[e + 3 * NROWS] = v.w;
        }
    }

    __syncthreads();

    // ---- write: stream chunk as float4, decode in-register ----
    float* __restrict__ dst = out + (size_t)slice * SLICE_N + GI0 * NROWS;

    #pragma unroll
    for (int it = 0; it < NIT; ++it) {
        const int i = t + it * 256;
        if (it < NIT - 1 || i < TOTQ) {
            const f32x4 u = *reinterpret_cast<const f32x4*>(&tile[4 * i]);
            const int e   = 4 * i;                 // local element index
            const int gi0 = e / NROWS;             // magic div (0..NG-1)
            const int c0  = e - gi0 * NROWS;

            const float xs[4] = {u.x, u.y, u.z, u.w};
            float r[4];
            #pragma unroll
            for (int k = 0; k < 4; ++k) {
                int c  = c0 + k;
                int gi = gi0;
                if (c >= NROWS) { c -= NROWS; gi += 1; }
                const int a    = (c >= 170) ? 2 : (c >= 85 ? 1 : 0);
                const int attr = c - a * 85;

                const float x  = xs[k];
                const float s  = fast_sigmoid(x);
                const float ex = __builtin_amdgcn_exp2f(L2E * x);
                const float ancx = (a == 0) ? a0x : (a == 1) ? a1x : a2x;
                const float ancy = (a == 0) ? a0y : (a == 1) ? a1y : a2y;

                float r_;
                if (attr >= 4)      r_ = s;
                else if (attr == 0) r_ = (s + (float)(GI0 + gi)) * 8.0f;
                else if (attr == 1) r_ = (s + (float)gj) * 8.0f;
                else if (attr == 2) r_ = ex * ancx;
                else                r_ = ex * ancy;
                r[k] = r_;
            }

            f32x4 o; o.x = r[0]; o.y = r[1]; o.z = r[2]; o.w = r[3];
            __builtin_nontemporal_store(o, reinterpret_cast<f32x4*>(dst + 4 * i));
        }
    }
}

__global__ __launch_bounds__(256, 8)
void detect_decode_kernel(const float* __restrict__ in,
                          const float* __restrict__ anchors,
                          float* __restrict__ out) {
    __shared__ float tile[16 * NROWS];   // 16,320 B (max chunk)

    // XCD-bijective swizzle: grid = 6656 = 8*832. xcd = B&7; the 4 chunks of
    // a slice occupy consecutive slots on the SAME xcd.
    const int B     = blockIdx.x;
    const int xcd   = B & 7;
    const int slot  = B >> 3;            // 0..831
    const int chunk = slot & 3;
    const int slice = ((slot >> 2) << 3) | xcd;   // 0..1663
    const int t     = threadIdx.x;

    const float* anc = anchors;
    if      (chunk == 0) decode_body< 0, 16>(slice, t, in, anc, out, tile);
    else if (chunk == 1) decode_body<16, 12>(slice, t, in, anc, out, tile);
    else if (chunk == 2) decode_body<28, 12>(slice, t, in, anc, out, tile);
    else                 decode_body<40, 12>(slice, t, in, anc, out, tile);
}

extern "C" void kernel_launch(void* const* d_in, const int* in_sizes, int n_in,
                              void* d_out, int out_size, void* d_ws, size_t ws_size,
                              hipStream_t stream) {
    const float* pred    = (const float*)d_in[0];
    const float* anchors = (const float*)d_in[1];
    float* out = (float*)d_out;

    const int nblocks = BB * GG * 4;   // 6656
    detect_decode_kernel<<<nblocks, 256, 0, stream>>>(pred, anchors, out);
}